// Round 3
// baseline (181.507 us; speedup 1.0000x reference)
//
#include <hip/hip_runtime.h>
#include <hip/hip_bf16.h>

// EgoAttentionNetwork: B=8192, E=64, F_IN=7, D=64, H=4, HD=16. fp32 in/out.
// Round 9: occupancy play. 2 batches/wave (was 4), grid 4096 (was 2048) ->
// 16 blocks/CU demanded; LDS dieted 18.4KB -> ~12KB so ~13 blocks/CU resident
// (was 8, grid-capped). Chain (egoL1/egoL2/KQ, 44 MFMAs) now amortized over 2
// batches: +19% MFMA work for +63% occupancy.
// LDS diet: kqb/py 8 rows; pa 4 rows (read ln&3, don't materialize copies);
// chainbuf/ob aliased (2 rows); compact buffers stride 64 u16 (rows 128B,
// 16B-aligned for b128); mask column -> per-lane 16-bit register bitmask.
// P2/S restructured mt-outer (frag regs live 8 not 32) to fit VGPR<=128 at
// __launch_bounds__(64,4). Wave-local LDS_FENCE (r8-validated) kept.

typedef __attribute__((ext_vector_type(8))) short short8;   // 8 bf16
typedef __attribute__((ext_vector_type(4))) short short4b;  // 4 bf16
typedef __attribute__((ext_vector_type(4))) float f32x4;

#define SY 72          // u16 row stride for hy (bank-spread, 16B-aligned rows)
#define SK 64          // u16 row stride for compact buffers (128B rows)

// wave-local LDS fence: order DS ops at compile time, drain LDS counter only.
#define LDS_FENCE() asm volatile("s_waitcnt lgkmcnt(0)" ::: "memory")

// ws offsets in u16 units (total 33792 u16 = 67584 B)
#define WS_G    0      // [256][64]  G[(h*64+f)][j]
#define WS_EGW0 16384  // [64][8]    ego_w0^T (k<7 real, k=7 zero)
#define WS_EGW1 16896  // [64][64]   ego_w1^T
#define WS_WVT  20992  // [64][64]   Wv^T
#define WS_WCT  25088  // [64][64]   Wc^T
#define WS_W0T  29184  // [64][8]    oth_w0^T
#define WS_W1T  29696  // [64][64]   oth_w1^T

__device__ __forceinline__ short f2bs(float x) {
    __hip_bfloat16 h = __float2bfloat16(x);
    return __builtin_bit_cast(short, h);
}
__device__ __forceinline__ unsigned short f2u(float x) {
    __hip_bfloat16 h = __float2bfloat16(x);
    return __builtin_bit_cast(unsigned short, h);
}
__device__ __forceinline__ short8 ldws8(const unsigned short* p) {
    return *(const short8*)p;   // 16B-aligned -> global_load_dwordx4
}

__global__ void pack_ws(const float* __restrict__ ego_w0, const float* __restrict__ ego_w1,
                        const float* __restrict__ oth_w0, const float* __restrict__ oth_w1,
                        const float* __restrict__ Wk, const float* __restrict__ Wv,
                        const float* __restrict__ Wq, const float* __restrict__ Wc,
                        unsigned short* __restrict__ ws) {
    const int blk = blockIdx.x, t = threadIdx.x;
    if (blk < 256) {
        // G[n=(h*64+f)][j] = sum_d Wq[j][16h+d] * Wk[f][16h+d]
        const int n = blk, h = n >> 6, f = n & 63, j = t;
        float a = 0.f;
#pragma unroll
        for (int d = 0; d < 16; ++d)
            a = fmaf(Wq[j * 64 + h * 16 + d], Wk[f * 64 + h * 16 + d], a);
        ws[WS_G + n * 64 + j] = f2u(a);
    } else {
        const int n = blk - 256, k = t;    // n = output col, k = contraction idx
        ws[WS_EGW1 + n * 64 + k] = f2u(ego_w1[k * 64 + n]);
        ws[WS_WVT  + n * 64 + k] = f2u(Wv[k * 64 + n]);
        ws[WS_WCT  + n * 64 + k] = f2u(Wc[k * 64 + n]);
        ws[WS_W1T  + n * 64 + k] = f2u(oth_w1[k * 64 + n]);
        if (k < 8) {
            ws[WS_EGW0 + n * 8 + k] = (k < 7) ? f2u(ego_w0[k * 64 + n]) : 0;
            ws[WS_W0T  + n * 8 + k] = (k < 7) ? f2u(oth_w0[k * 64 + n]) : 0;
        }
    }
}

__global__ __launch_bounds__(64, 4)
void ego_attn_kernel(const float* __restrict__ x,
                     const float* __restrict__ ego_b0, const float* __restrict__ ego_b1,
                     const float* __restrict__ oth_b0, const float* __restrict__ oth_b1,
                     const unsigned short* __restrict__ ws,
                     float* __restrict__ out)
{
    __shared__ __align__(16) short hy[64 * SY];    // H then Y, row-major bf16 (9216 B)
    __shared__ __align__(16) short kqb[8 * SK];    // row i*4+h : kq[i][h][f]*0.25
    __shared__ __align__(16) short pa[4 * SK];     // P[h][e], 4 real rows
    __shared__ __align__(16) short py[8 * SK];     // row h*2+i : pY[i][h][f]
    __shared__ __align__(16) short cbob[2 * SK];   // chainbuf (chain) / ob (tail)

    const int lane = threadIdx.x;
    const int lg = lane >> 4, ln = lane & 15;
    const int gb = blockIdx.x * 2;                 // 2 batches per wave

    const short8 z8 = {0, 0, 0, 0, 0, 0, 0, 0};

    // ---- persistent frags (from ws, 16B vector loads) ----
    short8 w0f[4], w1f[2][4];
#pragma unroll
    for (int ct = 0; ct < 4; ++ct)
        w0f[ct] = (lg == 0) ? ldws8(ws + WS_W0T + (ct * 16 + ln) * 8) : z8;
#pragma unroll
    for (int kc = 0; kc < 2; ++kc)
#pragma unroll
        for (int ct = 0; ct < 4; ++ct)
            w1f[kc][ct] = ldws8(ws + WS_W1T + (ct * 16 + ln) * 64 + kc * 32 + lg * 8);
    float b0v[4], b1v[4], eb0v[4], eb1v[4];
#pragma unroll
    for (int ct = 0; ct < 4; ++ct) {
        b0v[ct]  = oth_b0[ct * 16 + ln];
        b1v[ct]  = oth_b1[ct * 16 + ln];
        eb0v[ct] = ego_b0[ct * 16 + ln];
        eb1v[ct] = ego_b1[ct * 16 + ln];
    }

    // ---- prefetch per-wave x data: A-frags + mask bitmask (no LDS) ----
    short8 xab[2][4];                              // [batch][mt], lg==0 rows real
    unsigned mbits[2];                             // bit mt*4+r: entity absent
#pragma unroll
    for (int i = 0; i < 2; ++i) {
        const float* xb = x + (size_t)(gb + i) * 448;
        unsigned mb = 0;
#pragma unroll
        for (int mt = 0; mt < 4; ++mt) {
            short8 v = z8;
            if (lg == 0) {
                const float* xr = xb + (mt * 16 + ln) * 7;
#pragma unroll
                for (int k = 0; k < 7; ++k) v[k] = f2bs(xr[k]);
            }
            xab[i][mt] = v;
#pragma unroll
            for (int r = 0; r < 4; ++r) {
                const float mv = xb[(mt * 16 + lg * 4 + r) * 7];
                if (mv < 0.5f) mb |= 1u << (mt * 4 + r);
            }
        }
        mbits[i] = mb;
    }

    // ================= chain: egoL1 -> egoL2 -> KQ (both batches) ===========
    short8 xea = z8;                               // A[m=b][k<7] = x_b row 0
    if (lg == 0 && ln < 2) {
        const float* xr = x + (size_t)(gb + ln) * 448;
#pragma unroll
        for (int k = 0; k < 7; ++k) xea[k] = f2bs(xr[k]);
    }
#pragma unroll
    for (int ct = 0; ct < 4; ++ct) {              // Hego = relu(x0 @ ego_w0 + b0)
        const short8 bfr = (lg == 0) ? ldws8(ws + WS_EGW0 + (ct * 16 + ln) * 8) : z8;
        f32x4 c = {eb0v[ct], eb0v[ct], eb0v[ct], eb0v[ct]};
        c = __builtin_amdgcn_mfma_f32_16x16x32_bf16(xea, bfr, c, 0, 0, 0);
        if (lg == 0) {
#pragma unroll
            for (int r = 0; r < 2; ++r)
                cbob[r * SK + ct * 16 + ln] = f2bs(fmaxf(c[r], 0.f));
        }
    }
    LDS_FENCE();
    short8 ha[2];
#pragma unroll
    for (int kc = 0; kc < 2; ++kc)
        ha[kc] = *(const short8*)&cbob[(ln & 1) * SK + kc * 32 + lg * 8];
    LDS_FENCE();

    float egoR[4][2];                              // Ego (post-relu), [ct][batch]
#pragma unroll
    for (int ct = 0; ct < 4; ++ct) {              // Ego = relu(Hego @ ego_w1 + b1)
        f32x4 c = {eb1v[ct], eb1v[ct], eb1v[ct], eb1v[ct]};
#pragma unroll
        for (int kc = 0; kc < 2; ++kc) {
            const short8 bfr = ldws8(ws + WS_EGW1 + (ct * 16 + ln) * 64 + kc * 32 + lg * 8);
            c = __builtin_amdgcn_mfma_f32_16x16x32_bf16(ha[kc], bfr, c, 0, 0, 0);
        }
#pragma unroll
        for (int r = 0; r < 2; ++r) egoR[ct][r] = fmaxf(c[r], 0.f);
    }
    if (lg == 0) {
#pragma unroll
        for (int ct = 0; ct < 4; ++ct)
#pragma unroll
            for (int r = 0; r < 2; ++r)
                cbob[r * SK + ct * 16 + ln] = f2bs(egoR[ct][r]);
    }
    LDS_FENCE();
    short8 ea[2];
#pragma unroll
    for (int kc = 0; kc < 2; ++kc)
        ea[kc] = *(const short8*)&cbob[(ln & 1) * SK + kc * 32 + lg * 8];

    // KQ[b][n=(h*64+f)] = sum_j Ego[b][j] G[n][j]; fold 0.25 score scale here
#pragma unroll
    for (int ctg = 0; ctg < 16; ++ctg) {
        f32x4 c = {0.f, 0.f, 0.f, 0.f};
#pragma unroll
        for (int kc = 0; kc < 2; ++kc) {
            const short8 bfr = ldws8(ws + WS_G + (ctg * 16 + ln) * 64 + kc * 32 + lg * 8);
            c = __builtin_amdgcn_mfma_f32_16x16x32_bf16(ea[kc], bfr, c, 0, 0, 0);
        }
        if (lg == 0) {
            const int h = ctg >> 2, fc = (ctg & 3) * 16 + ln;
#pragma unroll
            for (int r = 0; r < 2; ++r)
                kqb[(r * 4 + h) * SK + fc] = f2bs(c[r] * 0.25f);
        }
    }
    LDS_FENCE();

    // ================= per-batch: P1, P2, S+softmax, pY ======================
#pragma unroll
    for (int i = 0; i < 2; ++i) {
        // P1: H = relu(X @ W0 + b0)
#pragma unroll
        for (int mt = 0; mt < 4; ++mt)
#pragma unroll
            for (int ct = 0; ct < 4; ++ct) {
                f32x4 c = {b0v[ct], b0v[ct], b0v[ct], b0v[ct]};
                c = __builtin_amdgcn_mfma_f32_16x16x32_bf16(xab[i][mt], w0f[ct], c, 0, 0, 0);
#pragma unroll
                for (int r = 0; r < 4; ++r)
                    hy[(mt * 16 + lg * 4 + r) * SY + ct * 16 + ln] = f2bs(fmaxf(c[r], 0.f));
            }
        LDS_FENCE();
        // P2: Y = relu(H @ W1 + b1), mt-outer (reads/writes disjoint 16-row
        // slice per mt; same-wave DS pipe is in-order so read-then-write is
        // safe without a fence). Then row 0 <- ego_i.
#pragma unroll
        for (int mt = 0; mt < 4; ++mt) {
            short8 a20 = *(const short8*)&hy[(mt * 16 + ln) * SY + 0 * 32 + lg * 8];
            short8 a21 = *(const short8*)&hy[(mt * 16 + ln) * SY + 1 * 32 + lg * 8];
#pragma unroll
            for (int ct = 0; ct < 4; ++ct) {
                f32x4 c = {b1v[ct], b1v[ct], b1v[ct], b1v[ct]};
                c = __builtin_amdgcn_mfma_f32_16x16x32_bf16(a20, w1f[0][ct], c, 0, 0, 0);
                c = __builtin_amdgcn_mfma_f32_16x16x32_bf16(a21, w1f[1][ct], c, 0, 0, 0);
#pragma unroll
                for (int r = 0; r < 4; ++r)
                    hy[(mt * 16 + lg * 4 + r) * SY + ct * 16 + ln] = f2bs(fmaxf(c[r], 0.f));
            }
        }
        if (lg == 0) {
#pragma unroll
            for (int ct = 0; ct < 4; ++ct)
                hy[ct * 16 + ln] = f2bs(egoR[ct][i]);   // Y row 0 = ego_i
        }
        LDS_FENCE();
        // S = Y @ kq_i^T (n=h, cols>=4 copies); softmax per head (col ln&3)
        short8 kb[2];
#pragma unroll
        for (int kc = 0; kc < 2; ++kc)
            kb[kc] = *(const short8*)&kqb[(i * 4 + (ln & 3)) * SK + kc * 32 + lg * 8];

        float sv[16];
        float m = -3e38f;
#pragma unroll
        for (int mt = 0; mt < 4; ++mt) {
            const short8 ya0 = *(const short8*)&hy[(mt * 16 + ln) * SY + 0 * 32 + lg * 8];
            const short8 ya1 = *(const short8*)&hy[(mt * 16 + ln) * SY + 1 * 32 + lg * 8];
            f32x4 c = {0.f, 0.f, 0.f, 0.f};
            c = __builtin_amdgcn_mfma_f32_16x16x32_bf16(ya0, kb[0], c, 0, 0, 0);
            c = __builtin_amdgcn_mfma_f32_16x16x32_bf16(ya1, kb[1], c, 0, 0, 0);
#pragma unroll
            for (int r = 0; r < 4; ++r) {
                float s = c[r];                          // 0.25 folded into kqb
                if ((mbits[i] >> (mt * 4 + r)) & 1u) s = -1e9f;
                sv[mt * 4 + r] = s;
                m = fmaxf(m, s);
            }
        }
        m = fmaxf(m, __shfl_xor(m, 16));
        m = fmaxf(m, __shfl_xor(m, 32));
        float sum = 0.f;
#pragma unroll
        for (int k = 0; k < 16; ++k) { sv[k] = __expf(sv[k] - m); sum += sv[k]; }
        sum += __shfl_xor(sum, 16);
        sum += __shfl_xor(sum, 32);
        const float inv = 1.f / sum;
        if (ln < 4) {                               // 4 real rows only
#pragma unroll
            for (int mt = 0; mt < 4; ++mt) {
                short4b pk;
#pragma unroll
                for (int r = 0; r < 4; ++r) pk[r] = f2bs(sv[mt * 4 + r] * inv);
                *(short4b*)&pa[ln * SK + mt * 16 + lg * 4] = pk;   // P[h=ln][e]
            }
        }
        LDS_FENCE();
        // pY = P @ Y  (A row m -> head m&3 via replicated read)
        short8 pf[2];
#pragma unroll
        for (int kc = 0; kc < 2; ++kc)
            pf[kc] = *(const short8*)&pa[(ln & 3) * SK + kc * 32 + lg * 8];
#pragma unroll
        for (int ct = 0; ct < 4; ++ct) {
            f32x4 c = {0.f, 0.f, 0.f, 0.f};
#pragma unroll
            for (int kc = 0; kc < 2; ++kc) {
                short8 yv;
#pragma unroll
                for (int j = 0; j < 8; ++j)
                    yv[j] = hy[(kc * 32 + lg * 8 + j) * SY + ct * 16 + ln];
                c = __builtin_amdgcn_mfma_f32_16x16x32_bf16(pf[kc], yv, c, 0, 0, 0);
            }
            if (lg == 0) {
#pragma unroll
                for (int r = 0; r < 4; ++r)
                    py[(r * 2 + i) * SK + ct * 16 + ln] = f2bs(c[r]);   // [h][b][f]
            }
        }
        LDS_FENCE();
    }

    // ================= tail: o64 = pY @ Wv (head-sliced), result ============
#pragma unroll
    for (int ct = 0; ct < 4; ++ct) {              // ct = head h; cols 16h..16h+16
        short8 af[2];
#pragma unroll
        for (int kc = 0; kc < 2; ++kc)
            af[kc] = *(const short8*)&py[(ct * 2 + (ln & 1)) * SK + kc * 32 + lg * 8];
        f32x4 c = {0.f, 0.f, 0.f, 0.f};
#pragma unroll
        for (int kc = 0; kc < 2; ++kc) {
            const short8 bfr = ldws8(ws + WS_WVT + (ct * 16 + ln) * 64 + kc * 32 + lg * 8);
            c = __builtin_amdgcn_mfma_f32_16x16x32_bf16(af[kc], bfr, c, 0, 0, 0);
        }
        if (lg == 0) {
#pragma unroll
            for (int r = 0; r < 2; ++r)
                cbob[r * SK + ct * 16 + ln] = f2bs(c[r]);   // ob rows = batch
        }
    }
    LDS_FENCE();
    short8 oa[2];
#pragma unroll
    for (int kc = 0; kc < 2; ++kc)
        oa[kc] = *(const short8*)&cbob[(ln & 1) * SK + kc * 32 + lg * 8];
#pragma unroll
    for (int ct = 0; ct < 4; ++ct) {              // result = o64 @ Wc + ego, *0.5
        f32x4 c = {0.f, 0.f, 0.f, 0.f};
#pragma unroll
        for (int kc = 0; kc < 2; ++kc) {
            const short8 bfr = ldws8(ws + WS_WCT + (ct * 16 + ln) * 64 + kc * 32 + lg * 8);
            c = __builtin_amdgcn_mfma_f32_16x16x32_bf16(oa[kc], bfr, c, 0, 0, 0);
        }
        if (lg == 0) {
#pragma unroll
            for (int r = 0; r < 2; ++r)
                out[(size_t)(gb + r) * 64 + ct * 16 + ln] = (c[r] + egoR[ct][r]) * 0.5f;
        }
    }
}

extern "C" void kernel_launch(void* const* d_in, const int* in_sizes, int n_in,
                              void* d_out, int out_size, void* d_ws, size_t ws_size,
                              hipStream_t stream) {
    const float* x      = (const float*)d_in[0];
    const float* ego_w0 = (const float*)d_in[1];
    const float* ego_b0 = (const float*)d_in[2];
    const float* ego_w1 = (const float*)d_in[3];
    const float* ego_b1 = (const float*)d_in[4];
    const float* oth_w0 = (const float*)d_in[5];
    const float* oth_b0 = (const float*)d_in[6];
    const float* oth_w1 = (const float*)d_in[7];
    const float* oth_b1 = (const float*)d_in[8];
    const float* Wk     = (const float*)d_in[9];
    const float* Wv     = (const float*)d_in[10];
    const float* Wq     = (const float*)d_in[11];
    const float* Wc     = (const float*)d_in[12];

    unsigned short* ws = (unsigned short*)d_ws;   // needs 67584 B
    pack_ws<<<320, 64, 0, stream>>>(ego_w0, ego_w1, oth_w0, oth_w1,
                                    Wk, Wv, Wq, Wc, ws);
    ego_attn_kernel<<<4096, 64, 0, stream>>>(
        x, ego_b0, ego_b1, oth_b0, oth_b1, ws, (float*)d_out);
}

// Round 4
// 141.020 us; speedup vs baseline: 1.2871x; 1.2871x over previous
//
#include <hip/hip_runtime.h>
#include <hip/hip_bf16.h>

// EgoAttentionNetwork: B=8192, E=64, F_IN=7, D=64, H=4, HD=16. fp32 in/out.
// Round 10: LDS-instruction diet on the proven r6/r8 single-wave structure.
// Theory: co-limits are the CU-shared LDS pipe (~1150 LDS instrs/wave, mostly
// scalar ds_write_b16 C-spills + pY's 64x ds_read_u16 gather) and the serial
// per-stage LDS chains. Fix: per stage, compute the TRANSPOSED orientation so
// MFMA C-frags (4 consecutive rows of one column per lane) pack into the
// consumer's k-contiguous layout as ds_write_b64:
//  - P1 swapped (H^T = W0^T @ X^T; identical input frags): 16 w64 vs 64 w16.
//  - P2 dual: same regs (a2,w1f) in both orientations -> packed w64 into BOTH
//    hy[e][d] (for S) and yt[f][e] (for pY). pY gather 64 r16 -> 8 r128.
//  - KQ swapped: kqb 16 w64 vs 64 w16.
//  - XOR swizzle (d ^= (e&7)<<3) replaces +8 padding: hy/yt 8KB each,
//    conflict-free b128; total LDS 20992 B (7 blocks/CU, grid-capped anyway).
//  - mask via one __ballot per batch (reg bitmask, no mbuf).
// ~620 LDS instrs/wave (was ~1150), shorter chains, 444 MFMAs (was 316).

typedef __attribute__((ext_vector_type(8))) short short8;   // 8 bf16
typedef __attribute__((ext_vector_type(4))) short short4b;  // 4 bf16
typedef __attribute__((ext_vector_type(4))) float f32x4;

// wave-local LDS fence: order DS ops at compile time, drain LDS counter only.
#define LDS_FENCE() asm volatile("s_waitcnt lgkmcnt(0)" ::: "memory")

// ws offsets in u16 units (total 33792 u16 = 67584 B)
#define WS_G    0      // [256][64]  G[(h*64+f)][j]
#define WS_EGW0 16384  // [64][8]    ego_w0^T (k<7 real, k=7 zero)
#define WS_EGW1 16896  // [64][64]   ego_w1^T
#define WS_WVT  20992  // [64][64]   Wv^T
#define WS_WCT  25088  // [64][64]   Wc^T
#define WS_W0T  29184  // [64][8]    oth_w0^T
#define WS_W1T  29696  // [64][64]   oth_w1^T

__device__ __forceinline__ short f2bs(float x) {
    __hip_bfloat16 h = __float2bfloat16(x);
    return __builtin_bit_cast(short, h);
}
__device__ __forceinline__ unsigned short f2u(float x) {
    __hip_bfloat16 h = __float2bfloat16(x);
    return __builtin_bit_cast(unsigned short, h);
}
__device__ __forceinline__ short8 ldws8(const unsigned short* p) {
    return *(const short8*)p;   // 16B-aligned -> global_load_dwordx4
}
__device__ __forceinline__ short4b pk4r(f32x4 c) {      // relu + pack
    short4b p;
#pragma unroll
    for (int r = 0; r < 4; ++r) p[r] = f2bs(fmaxf(c[r], 0.f));
    return p;
}
__device__ __forceinline__ short4b pk4(f32x4 c) {       // pack
    short4b p;
#pragma unroll
    for (int r = 0; r < 4; ++r) p[r] = f2bs(c[r]);
    return p;
}

__global__ void pack_ws(const float* __restrict__ ego_w0, const float* __restrict__ ego_w1,
                        const float* __restrict__ oth_w0, const float* __restrict__ oth_w1,
                        const float* __restrict__ Wk, const float* __restrict__ Wv,
                        const float* __restrict__ Wq, const float* __restrict__ Wc,
                        unsigned short* __restrict__ ws) {
    const int blk = blockIdx.x, t = threadIdx.x;
    if (blk < 256) {
        // G[n=(h*64+f)][j] = sum_d Wq[j][16h+d] * Wk[f][16h+d]
        const int n = blk, h = n >> 6, f = n & 63, j = t;
        float a = 0.f;
#pragma unroll
        for (int d = 0; d < 16; ++d)
            a = fmaf(Wq[j * 64 + h * 16 + d], Wk[f * 64 + h * 16 + d], a);
        ws[WS_G + n * 64 + j] = f2u(a);
    } else {
        const int n = blk - 256, k = t;    // n = output col, k = contraction idx
        ws[WS_EGW1 + n * 64 + k] = f2u(ego_w1[k * 64 + n]);
        ws[WS_WVT  + n * 64 + k] = f2u(Wv[k * 64 + n]);
        ws[WS_WCT  + n * 64 + k] = f2u(Wc[k * 64 + n]);
        ws[WS_W1T  + n * 64 + k] = f2u(oth_w1[k * 64 + n]);
        if (k < 8) {
            ws[WS_EGW0 + n * 8 + k] = (k < 7) ? f2u(ego_w0[k * 64 + n]) : 0;
            ws[WS_W0T  + n * 8 + k] = (k < 7) ? f2u(oth_w0[k * 64 + n]) : 0;
        }
    }
}

__global__ __launch_bounds__(64, 2)
void ego_attn_kernel(const float* __restrict__ x,
                     const float* __restrict__ ego_b0, const float* __restrict__ ego_b1,
                     const float* __restrict__ oth_b0, const float* __restrict__ oth_b1,
                     const unsigned short* __restrict__ ws,
                     float* __restrict__ out)
{
    // hy: Y (and H) as [e][d], d-blocks XOR-swizzled by e&7. 8 KB.
    // yt: Y^T as [f][e], e-blocks XOR-swizzled by f&7. 8 KB.
    // kqb: rows b*4+h, 64 f's (chain output); re-used as ob rows b in tail.
    // pyb: rows h*4+b, 64 f's.
    // s4:  chain Hego/Ego rows b; re-used as pa rows h per batch.
    __shared__ __align__(16) short hy[4096];
    __shared__ __align__(16) short yt[4096];
    __shared__ __align__(16) short kqb[1024];
    __shared__ __align__(16) short pyb[1024];
    __shared__ __align__(16) short s4[256];

    const int lane = threadIdx.x;
    const int lg = lane >> 4, ln = lane & 15;
    const int gb = blockIdx.x * 4;                 // 4 batches per wave
    const short8 z8 = {0, 0, 0, 0, 0, 0, 0, 0};

    // ---- persistent frags (16B vector loads from ws) ----
    short8 w0f[4], w1f[2][4];                      // used as A or B (same map)
#pragma unroll
    for (int t = 0; t < 4; ++t)
        w0f[t] = (lg == 0) ? ldws8(ws + WS_W0T + (t * 16 + ln) * 8) : z8;
#pragma unroll
    for (int kc = 0; kc < 2; ++kc)
#pragma unroll
        for (int t = 0; t < 4; ++t)
            w1f[kc][t] = ldws8(ws + WS_W1T + (t * 16 + ln) * 64 + kc * 32 + lg * 8);
    float b1v[4], eb1v[4];                         // col-biases (unswapped use)
#pragma unroll
    for (int t = 0; t < 4; ++t) {
        b1v[t]  = oth_b1[t * 16 + ln];
        eb1v[t] = ego_b1[t * 16 + ln];
    }

    // ---- prefetch x: A/B-frags + ballot mask bits ----
    short8 xab[4][4];                              // [batch][e-tile]
    unsigned long long mb64[4];                    // bit e: entity absent
#pragma unroll
    for (int i = 0; i < 4; ++i) {
        const float* xb = x + (size_t)(gb + i) * 448;
        mb64[i] = __ballot(xb[lane * 7] < 0.5f);   // lane = e
#pragma unroll
        for (int mt = 0; mt < 4; ++mt) {
            short8 v = z8;
            if (lg == 0) {
                const float* xr = xb + (mt * 16 + ln) * 7;
#pragma unroll
                for (int k = 0; k < 7; ++k) v[k] = f2bs(xr[k]);
            }
            xab[i][mt] = v;
        }
    }
    short8 xea = z8;                               // x row0 per batch (n=b,k)
    if (lg == 0 && ln < 4) {
        const float* xr = x + (size_t)(gb + ln) * 448;
#pragma unroll
        for (int k = 0; k < 7; ++k) xea[k] = f2bs(xr[k]);
    }

    // ================= chain: egoL1 -> egoL2 -> KQ ==========================
    // egoL1 SWAPPED: C = Hego^T (rows=d, cols=b) -> packed w64 into s4[b][d]
#pragma unroll
    for (int dt = 0; dt < 4; ++dt) {
        const short8 af = (lg == 0) ? ldws8(ws + WS_EGW0 + (dt * 16 + ln) * 8) : z8;
        const float4 bq = *(const float4*)&ego_b0[dt * 16 + lg * 4];
        f32x4 c = {bq.x, bq.y, bq.z, bq.w};
        c = __builtin_amdgcn_mfma_f32_16x16x32_bf16(af, xea, c, 0, 0, 0);
        if (ln < 4)
            *(short4b*)&s4[ln * 64 + dt * 16 + lg * 4] = pk4r(c);
    }
    LDS_FENCE();
    short8 ha[2];
#pragma unroll
    for (int kc = 0; kc < 2; ++kc)
        ha[kc] = *(const short8*)&s4[(ln & 3) * 64 + kc * 32 + lg * 8];
    LDS_FENCE();
    // egoL2 unswapped (egoR layout needed per-lane: d=ct*16+ln, b=r)
    float egoR[4][4];
#pragma unroll
    for (int ct = 0; ct < 4; ++ct) {
        f32x4 c = {eb1v[ct], eb1v[ct], eb1v[ct], eb1v[ct]};
#pragma unroll
        for (int kc = 0; kc < 2; ++kc) {
            const short8 b = ldws8(ws + WS_EGW1 + (ct * 16 + ln) * 64 + kc * 32 + lg * 8);
            c = __builtin_amdgcn_mfma_f32_16x16x32_bf16(ha[kc], b, c, 0, 0, 0);
        }
#pragma unroll
        for (int r = 0; r < 4; ++r) egoR[ct][r] = fmaxf(c[r], 0.f);
    }
    if (lg == 0) {
#pragma unroll
        for (int ct = 0; ct < 4; ++ct)
#pragma unroll
            for (int r = 0; r < 4; ++r)
                s4[r * 64 + ct * 16 + ln] = f2bs(egoR[ct][r]);
    }
    LDS_FENCE();
    short8 ea[2];
#pragma unroll
    for (int kc = 0; kc < 2; ++kc)
        ea[kc] = *(const short8*)&s4[(ln & 3) * 64 + kc * 32 + lg * 8];
    // KQ SWAPPED: C rows = (h*64+f), cols = b -> packed w64 into kqb[b*4+h][f]
#pragma unroll
    for (int ctg = 0; ctg < 16; ++ctg) {
        f32x4 c = {0.f, 0.f, 0.f, 0.f};
#pragma unroll
        for (int kc = 0; kc < 2; ++kc) {
            const short8 g = ldws8(ws + WS_G + (ctg * 16 + ln) * 64 + kc * 32 + lg * 8);
            c = __builtin_amdgcn_mfma_f32_16x16x32_bf16(g, ea[kc], c, 0, 0, 0);
        }
        if (ln < 4) {
            f32x4 cs;
#pragma unroll
            for (int r = 0; r < 4; ++r) cs[r] = c[r] * 0.25f;   // fold 1/sqrt(16)
            *(short4b*)&kqb[(ln * 4 + (ctg >> 2)) * 64 + (ctg & 3) * 16 + lg * 4] = pk4(cs);
        }
    }
    LDS_FENCE();

    // ================= per-batch: P1, P2-dual, S+softmax, pY ================
#pragma unroll
    for (int i = 0; i < 4; ++i) {
        // P1 SWAPPED: C = H^T (rows=d, cols=e) -> packed w64 into hy[e][d]
#pragma unroll
        for (int dt = 0; dt < 4; ++dt) {
            const float4 bq = *(const float4*)&oth_b0[dt * 16 + lg * 4];
#pragma unroll
            for (int et = 0; et < 4; ++et) {
                f32x4 c = {bq.x, bq.y, bq.z, bq.w};
                c = __builtin_amdgcn_mfma_f32_16x16x32_bf16(w0f[dt], xab[i][et], c, 0, 0, 0);
                *(short4b*)&hy[(et * 16 + ln) * 64 +
                               ((((dt * 2 + (lg >> 1)) ^ (ln & 7)) << 3) | ((lg & 1) << 2))] = pk4r(c);
            }
        }
        LDS_FENCE();
        short8 a2[4][2];
#pragma unroll
        for (int mt = 0; mt < 4; ++mt)
#pragma unroll
            for (int kc = 0; kc < 2; ++kc)
                a2[mt][kc] = *(const short8*)&hy[(mt * 16 + ln) * 64 +
                                                 (((kc * 4 + lg) ^ (ln & 7)) << 3)];
        LDS_FENCE();
        // P2 unswapped: C (rows=e, cols=dout) -> packed w64 into yt[f][e]
#pragma unroll
        for (int mt = 0; mt < 4; ++mt)
#pragma unroll
            for (int ct = 0; ct < 4; ++ct) {
                f32x4 c = {b1v[ct], b1v[ct], b1v[ct], b1v[ct]};
                c = __builtin_amdgcn_mfma_f32_16x16x32_bf16(a2[mt][0], w1f[0][ct], c, 0, 0, 0);
                c = __builtin_amdgcn_mfma_f32_16x16x32_bf16(a2[mt][1], w1f[1][ct], c, 0, 0, 0);
                *(short4b*)&yt[(ct * 16 + ln) * 64 +
                               ((((mt * 2 + (lg >> 1)) ^ (ln & 7)) << 3) | ((lg & 1) << 2))] = pk4r(c);
            }
        // P2 swapped (same regs): C (rows=dout, cols=e) -> packed w64 into hy[e][d]
#pragma unroll
        for (int dt = 0; dt < 4; ++dt) {
            const float4 bq = *(const float4*)&oth_b1[dt * 16 + lg * 4];
#pragma unroll
            for (int et = 0; et < 4; ++et) {
                f32x4 c = {bq.x, bq.y, bq.z, bq.w};
                c = __builtin_amdgcn_mfma_f32_16x16x32_bf16(w1f[0][dt], a2[et][0], c, 0, 0, 0);
                c = __builtin_amdgcn_mfma_f32_16x16x32_bf16(w1f[1][dt], a2[et][1], c, 0, 0, 0);
                *(short4b*)&hy[(et * 16 + ln) * 64 +
                               ((((dt * 2 + (lg >> 1)) ^ (ln & 7)) << 3) | ((lg & 1) << 2))] = pk4r(c);
            }
        }
        if (lg == 0) {                             // Y row 0 / Y^T col 0 = ego_i
#pragma unroll
            for (int ct = 0; ct < 4; ++ct) {
                const short ev = f2bs(egoR[ct][i]);
                hy[ct * 16 + ln] = ev;                               // e=0: no swz
                yt[(ct * 16 + ln) * 64 + ((ln & 7) << 3)] = ev;      // e=0 slot
            }
        }
        LDS_FENCE();
        // S = Y @ kq_i^T (cols=h, >=4 copies); softmax per head (h = ln&3)
        short8 kb[2];
#pragma unroll
        for (int kc = 0; kc < 2; ++kc)
            kb[kc] = *(const short8*)&kqb[(i * 4 + (ln & 3)) * 64 + kc * 32 + lg * 8];
        float sv[16];
        float m = -3e38f;
#pragma unroll
        for (int mt = 0; mt < 4; ++mt) {
            const short8 ya0 = *(const short8*)&hy[(mt * 16 + ln) * 64 + (((lg) ^ (ln & 7)) << 3)];
            const short8 ya1 = *(const short8*)&hy[(mt * 16 + ln) * 64 + (((4 + lg) ^ (ln & 7)) << 3)];
            f32x4 c = {0.f, 0.f, 0.f, 0.f};
            c = __builtin_amdgcn_mfma_f32_16x16x32_bf16(ya0, kb[0], c, 0, 0, 0);
            c = __builtin_amdgcn_mfma_f32_16x16x32_bf16(ya1, kb[1], c, 0, 0, 0);
#pragma unroll
            for (int r = 0; r < 4; ++r) {
                float s = c[r];                    // 0.25 folded into kqb
                if ((mb64[i] >> (mt * 16 + lg * 4 + r)) & 1ull) s = -1e9f;
                sv[mt * 4 + r] = s;
                m = fmaxf(m, s);
            }
        }
        m = fmaxf(m, __shfl_xor(m, 16));
        m = fmaxf(m, __shfl_xor(m, 32));
        float sum = 0.f;
#pragma unroll
        for (int k = 0; k < 16; ++k) { sv[k] = __expf(sv[k] - m); sum += sv[k]; }
        sum += __shfl_xor(sum, 16);
        sum += __shfl_xor(sum, 32);
        const float inv = 1.f / sum;
        if (ln < 4) {                              // pa rows h = ln (in s4)
#pragma unroll
            for (int mt = 0; mt < 4; ++mt) {
                short4b pk;
#pragma unroll
                for (int r = 0; r < 4; ++r) pk[r] = f2bs(sv[mt * 4 + r] * inv);
                *(short4b*)&s4[ln * 64 + mt * 16 + lg * 4] = pk;
            }
        }
        LDS_FENCE();
        // pY = P @ Y: A = pa (b128), B = Y^T from yt (b128) -> pyb[h*4+b][f]
        short8 pf[2];
#pragma unroll
        for (int kc = 0; kc < 2; ++kc)
            pf[kc] = *(const short8*)&s4[(ln & 3) * 64 + kc * 32 + lg * 8];
#pragma unroll
        for (int ct = 0; ct < 4; ++ct) {
            f32x4 c = {0.f, 0.f, 0.f, 0.f};
#pragma unroll
            for (int kc = 0; kc < 2; ++kc) {
                const short8 yv = *(const short8*)&yt[(ct * 16 + ln) * 64 +
                                                      (((kc * 4 + lg) ^ (ln & 7)) << 3)];
                c = __builtin_amdgcn_mfma_f32_16x16x32_bf16(pf[kc], yv, c, 0, 0, 0);
            }
            if (lg == 0) {
#pragma unroll
                for (int r = 0; r < 4; ++r)
                    pyb[(r * 4 + i) * 64 + ct * 16 + ln] = f2bs(c[r]);
            }
        }
        LDS_FENCE();
    }

    // ================= tail: o64 = pY @ Wv (head-sliced), result ============
#pragma unroll
    for (int ct = 0; ct < 4; ++ct) {              // ct = head h
        short8 af[2];
#pragma unroll
        for (int kc = 0; kc < 2; ++kc)
            af[kc] = *(const short8*)&pyb[(ct * 4 + (ln & 3)) * 64 + kc * 32 + lg * 8];
        f32x4 c = {0.f, 0.f, 0.f, 0.f};
#pragma unroll
        for (int kc = 0; kc < 2; ++kc) {
            const short8 b = ldws8(ws + WS_WVT + (ct * 16 + ln) * 64 + kc * 32 + lg * 8);
            c = __builtin_amdgcn_mfma_f32_16x16x32_bf16(af[kc], b, c, 0, 0, 0);
        }
        if (lg == 0) {                             // ob rows b, in kqb region
#pragma unroll
            for (int r = 0; r < 4; ++r)
                kqb[r * 64 + ct * 16 + ln] = f2bs(c[r]);
        }
    }
    LDS_FENCE();
    short8 oa[2];
#pragma unroll
    for (int kc = 0; kc < 2; ++kc)
        oa[kc] = *(const short8*)&kqb[(ln & 3) * 64 + kc * 32 + lg * 8];
#pragma unroll
    for (int ct = 0; ct < 4; ++ct) {              // result = o64 @ Wc + ego, *0.5
        f32x4 c = {0.f, 0.f, 0.f, 0.f};
#pragma unroll
        for (int kc = 0; kc < 2; ++kc) {
            const short8 b = ldws8(ws + WS_WCT + (ct * 16 + ln) * 64 + kc * 32 + lg * 8);
            c = __builtin_amdgcn_mfma_f32_16x16x32_bf16(oa[kc], b, c, 0, 0, 0);
        }
        if (lg == 0) {
#pragma unroll
            for (int r = 0; r < 4; ++r)
                out[(size_t)(gb + r) * 64 + ct * 16 + ln] = (c[r] + egoR[ct][r]) * 0.5f;
        }
    }
}

extern "C" void kernel_launch(void* const* d_in, const int* in_sizes, int n_in,
                              void* d_out, int out_size, void* d_ws, size_t ws_size,
                              hipStream_t stream) {
    const float* x      = (const float*)d_in[0];
    const float* ego_w0 = (const float*)d_in[1];
    const float* ego_b0 = (const float*)d_in[2];
    const float* ego_w1 = (const float*)d_in[3];
    const float* ego_b1 = (const float*)d_in[4];
    const float* oth_w0 = (const float*)d_in[5];
    const float* oth_b0 = (const float*)d_in[6];
    const float* oth_w1 = (const float*)d_in[7];
    const float* oth_b1 = (const float*)d_in[8];
    const float* Wk     = (const float*)d_in[9];
    const float* Wv     = (const float*)d_in[10];
    const float* Wq     = (const float*)d_in[11];
    const float* Wc     = (const float*)d_in[12];

    unsigned short* ws = (unsigned short*)d_ws;   // needs 67584 B
    pack_ws<<<320, 64, 0, stream>>>(ego_w0, ego_w1, oth_w0, oth_w1,
                                    Wk, Wv, Wq, Wc, ws);
    ego_attn_kernel<<<2048, 64, 0, stream>>>(
        x, ego_b0, ego_b1, oth_b0, oth_b1, ws, (float*)d_out);
}

// Round 5
// 135.194 us; speedup vs baseline: 1.3426x; 1.0431x over previous
//
#include <hip/hip_runtime.h>
#include <hip/hip_bf16.h>

// EgoAttentionNetwork: B=8192, E=64, F_IN=7, D=64, H=4, HD=16. fp32 in/out.
// Round 11: r9 occupancy structure with the spill confound removed.
// r9 (2 batch/wave, grid 4096, LDS 12288 -> 13 blocks/CU) failed ONLY because
// __launch_bounds__(64,4) forced VGPR=64 -> massive scratch spills (WRITE_SIZE
// 70MB). Here: __launch_bounds__(64,2) (VGPR cap 256; compiler behavior proven
// spill-free at this setting in r6, 112 VGPR). Natural need ~110 <= 128 keeps
// the HW occupancy band at 16 waves/CU; LDS caps resident blocks at 13/CU
// (was 8 grid-capped in r6). Work/wave x1.19 (chain amortized over 2 batches).
// Also: r10-proven __ballot mask (1 load/batch) replaces 32 scalar mask loads.
// Everything else identical to r9 (which passed correctness).

typedef __attribute__((ext_vector_type(8))) short short8;   // 8 bf16
typedef __attribute__((ext_vector_type(4))) short short4b;  // 4 bf16
typedef __attribute__((ext_vector_type(4))) float f32x4;

#define SY 72          // u16 row stride for hy (bank-spread, 16B-aligned rows)
#define SK 64          // u16 row stride for compact buffers (128B rows)

// wave-local LDS fence: order DS ops at compile time, drain LDS counter only.
#define LDS_FENCE() asm volatile("s_waitcnt lgkmcnt(0)" ::: "memory")

// ws offsets in u16 units (total 33792 u16 = 67584 B)
#define WS_G    0      // [256][64]  G[(h*64+f)][j]
#define WS_EGW0 16384  // [64][8]    ego_w0^T (k<7 real, k=7 zero)
#define WS_EGW1 16896  // [64][64]   ego_w1^T
#define WS_WVT  20992  // [64][64]   Wv^T
#define WS_WCT  25088  // [64][64]   Wc^T
#define WS_W0T  29184  // [64][8]    oth_w0^T
#define WS_W1T  29696  // [64][64]   oth_w1^T

__device__ __forceinline__ short f2bs(float x) {
    __hip_bfloat16 h = __float2bfloat16(x);
    return __builtin_bit_cast(short, h);
}
__device__ __forceinline__ unsigned short f2u(float x) {
    __hip_bfloat16 h = __float2bfloat16(x);
    return __builtin_bit_cast(unsigned short, h);
}
__device__ __forceinline__ short8 ldws8(const unsigned short* p) {
    return *(const short8*)p;   // 16B-aligned -> global_load_dwordx4
}

__global__ void pack_ws(const float* __restrict__ ego_w0, const float* __restrict__ ego_w1,
                        const float* __restrict__ oth_w0, const float* __restrict__ oth_w1,
                        const float* __restrict__ Wk, const float* __restrict__ Wv,
                        const float* __restrict__ Wq, const float* __restrict__ Wc,
                        unsigned short* __restrict__ ws) {
    const int blk = blockIdx.x, t = threadIdx.x;
    if (blk < 256) {
        // G[n=(h*64+f)][j] = sum_d Wq[j][16h+d] * Wk[f][16h+d]
        const int n = blk, h = n >> 6, f = n & 63, j = t;
        float a = 0.f;
#pragma unroll
        for (int d = 0; d < 16; ++d)
            a = fmaf(Wq[j * 64 + h * 16 + d], Wk[f * 64 + h * 16 + d], a);
        ws[WS_G + n * 64 + j] = f2u(a);
    } else {
        const int n = blk - 256, k = t;    // n = output col, k = contraction idx
        ws[WS_EGW1 + n * 64 + k] = f2u(ego_w1[k * 64 + n]);
        ws[WS_WVT  + n * 64 + k] = f2u(Wv[k * 64 + n]);
        ws[WS_WCT  + n * 64 + k] = f2u(Wc[k * 64 + n]);
        ws[WS_W1T  + n * 64 + k] = f2u(oth_w1[k * 64 + n]);
        if (k < 8) {
            ws[WS_EGW0 + n * 8 + k] = (k < 7) ? f2u(ego_w0[k * 64 + n]) : 0;
            ws[WS_W0T  + n * 8 + k] = (k < 7) ? f2u(oth_w0[k * 64 + n]) : 0;
        }
    }
}

__global__ __launch_bounds__(64, 2)
void ego_attn_kernel(const float* __restrict__ x,
                     const float* __restrict__ ego_b0, const float* __restrict__ ego_b1,
                     const float* __restrict__ oth_b0, const float* __restrict__ oth_b1,
                     const unsigned short* __restrict__ ws,
                     float* __restrict__ out)
{
    __shared__ __align__(16) short hy[64 * SY];    // H then Y, row-major bf16 (9216 B)
    __shared__ __align__(16) short kqb[8 * SK];    // row i*4+h : kq[i][h][f]*0.25
    __shared__ __align__(16) short pa[4 * SK];     // P[h][e], 4 real rows
    __shared__ __align__(16) short py[8 * SK];     // row h*2+i : pY[i][h][f]
    __shared__ __align__(16) short cbob[2 * SK];   // chainbuf (chain) / ob (tail)

    const int lane = threadIdx.x;
    const int lg = lane >> 4, ln = lane & 15;
    const int gb = blockIdx.x * 2;                 // 2 batches per wave

    const short8 z8 = {0, 0, 0, 0, 0, 0, 0, 0};

    // ---- persistent frags (from ws, 16B vector loads) ----
    short8 w0f[4], w1f[2][4];
#pragma unroll
    for (int ct = 0; ct < 4; ++ct)
        w0f[ct] = (lg == 0) ? ldws8(ws + WS_W0T + (ct * 16 + ln) * 8) : z8;
#pragma unroll
    for (int kc = 0; kc < 2; ++kc)
#pragma unroll
        for (int ct = 0; ct < 4; ++ct)
            w1f[kc][ct] = ldws8(ws + WS_W1T + (ct * 16 + ln) * 64 + kc * 32 + lg * 8);
    float b0v[4], b1v[4], eb0v[4], eb1v[4];
#pragma unroll
    for (int ct = 0; ct < 4; ++ct) {
        b0v[ct]  = oth_b0[ct * 16 + ln];
        b1v[ct]  = oth_b1[ct * 16 + ln];
        eb0v[ct] = ego_b0[ct * 16 + ln];
        eb1v[ct] = ego_b1[ct * 16 + ln];
    }

    // ---- prefetch per-wave x data: A-frags + ballot mask bits ----
    short8 xab[2][4];                              // [batch][mt], lg==0 rows real
    unsigned long long mb64[2];                    // bit e: entity absent
#pragma unroll
    for (int i = 0; i < 2; ++i) {
        const float* xb = x + (size_t)(gb + i) * 448;
        mb64[i] = __ballot(xb[lane * 7] < 0.5f);   // lane = e
#pragma unroll
        for (int mt = 0; mt < 4; ++mt) {
            short8 v = z8;
            if (lg == 0) {
                const float* xr = xb + (mt * 16 + ln) * 7;
#pragma unroll
                for (int k = 0; k < 7; ++k) v[k] = f2bs(xr[k]);
            }
            xab[i][mt] = v;
        }
    }

    // ================= chain: egoL1 -> egoL2 -> KQ (both batches) ===========
    short8 xea = z8;                               // A[m=b][k<7] = x_b row 0
    if (lg == 0 && ln < 2) {
        const float* xr = x + (size_t)(gb + ln) * 448;
#pragma unroll
        for (int k = 0; k < 7; ++k) xea[k] = f2bs(xr[k]);
    }
#pragma unroll
    for (int ct = 0; ct < 4; ++ct) {              // Hego = relu(x0 @ ego_w0 + b0)
        const short8 bfr = (lg == 0) ? ldws8(ws + WS_EGW0 + (ct * 16 + ln) * 8) : z8;
        f32x4 c = {eb0v[ct], eb0v[ct], eb0v[ct], eb0v[ct]};
        c = __builtin_amdgcn_mfma_f32_16x16x32_bf16(xea, bfr, c, 0, 0, 0);
        if (lg == 0) {
#pragma unroll
            for (int r = 0; r < 2; ++r)
                cbob[r * SK + ct * 16 + ln] = f2bs(fmaxf(c[r], 0.f));
        }
    }
    LDS_FENCE();
    short8 ha[2];
#pragma unroll
    for (int kc = 0; kc < 2; ++kc)
        ha[kc] = *(const short8*)&cbob[(ln & 1) * SK + kc * 32 + lg * 8];
    LDS_FENCE();

    float egoR[4][2];                              // Ego (post-relu), [ct][batch]
#pragma unroll
    for (int ct = 0; ct < 4; ++ct) {              // Ego = relu(Hego @ ego_w1 + b1)
        f32x4 c = {eb1v[ct], eb1v[ct], eb1v[ct], eb1v[ct]};
#pragma unroll
        for (int kc = 0; kc < 2; ++kc) {
            const short8 bfr = ldws8(ws + WS_EGW1 + (ct * 16 + ln) * 64 + kc * 32 + lg * 8);
            c = __builtin_amdgcn_mfma_f32_16x16x32_bf16(ha[kc], bfr, c, 0, 0, 0);
        }
#pragma unroll
        for (int r = 0; r < 2; ++r) egoR[ct][r] = fmaxf(c[r], 0.f);
    }
    if (lg == 0) {
#pragma unroll
        for (int ct = 0; ct < 4; ++ct)
#pragma unroll
            for (int r = 0; r < 2; ++r)
                cbob[r * SK + ct * 16 + ln] = f2bs(egoR[ct][r]);
    }
    LDS_FENCE();
    short8 ea[2];
#pragma unroll
    for (int kc = 0; kc < 2; ++kc)
        ea[kc] = *(const short8*)&cbob[(ln & 1) * SK + kc * 32 + lg * 8];

    // KQ[b][n=(h*64+f)] = sum_j Ego[b][j] G[n][j]; fold 0.25 score scale here
#pragma unroll
    for (int ctg = 0; ctg < 16; ++ctg) {
        f32x4 c = {0.f, 0.f, 0.f, 0.f};
#pragma unroll
        for (int kc = 0; kc < 2; ++kc) {
            const short8 bfr = ldws8(ws + WS_G + (ctg * 16 + ln) * 64 + kc * 32 + lg * 8);
            c = __builtin_amdgcn_mfma_f32_16x16x32_bf16(ea[kc], bfr, c, 0, 0, 0);
        }
        if (lg == 0) {
            const int h = ctg >> 2, fc = (ctg & 3) * 16 + ln;
#pragma unroll
            for (int r = 0; r < 2; ++r)
                kqb[(r * 4 + h) * SK + fc] = f2bs(c[r] * 0.25f);
        }
    }
    LDS_FENCE();

    // ================= per-batch: P1, P2, S+softmax, pY ======================
#pragma unroll
    for (int i = 0; i < 2; ++i) {
        // P1: H = relu(X @ W0 + b0)
#pragma unroll
        for (int mt = 0; mt < 4; ++mt)
#pragma unroll
            for (int ct = 0; ct < 4; ++ct) {
                f32x4 c = {b0v[ct], b0v[ct], b0v[ct], b0v[ct]};
                c = __builtin_amdgcn_mfma_f32_16x16x32_bf16(xab[i][mt], w0f[ct], c, 0, 0, 0);
#pragma unroll
                for (int r = 0; r < 4; ++r)
                    hy[(mt * 16 + lg * 4 + r) * SY + ct * 16 + ln] = f2bs(fmaxf(c[r], 0.f));
            }
        LDS_FENCE();
        // P2: Y = relu(H @ W1 + b1), mt-outer (reads/writes disjoint 16-row
        // slice per mt; same-wave DS pipe is in-order so read-then-write is
        // safe without a fence). Then row 0 <- ego_i.
#pragma unroll
        for (int mt = 0; mt < 4; ++mt) {
            short8 a20 = *(const short8*)&hy[(mt * 16 + ln) * SY + 0 * 32 + lg * 8];
            short8 a21 = *(const short8*)&hy[(mt * 16 + ln) * SY + 1 * 32 + lg * 8];
#pragma unroll
            for (int ct = 0; ct < 4; ++ct) {
                f32x4 c = {b1v[ct], b1v[ct], b1v[ct], b1v[ct]};
                c = __builtin_amdgcn_mfma_f32_16x16x32_bf16(a20, w1f[0][ct], c, 0, 0, 0);
                c = __builtin_amdgcn_mfma_f32_16x16x32_bf16(a21, w1f[1][ct], c, 0, 0, 0);
#pragma unroll
                for (int r = 0; r < 4; ++r)
                    hy[(mt * 16 + lg * 4 + r) * SY + ct * 16 + ln] = f2bs(fmaxf(c[r], 0.f));
            }
        }
        if (lg == 0) {
#pragma unroll
            for (int ct = 0; ct < 4; ++ct)
                hy[ct * 16 + ln] = f2bs(egoR[ct][i]);   // Y row 0 = ego_i
        }
        LDS_FENCE();
        // S = Y @ kq_i^T (n=h, cols>=4 copies); softmax per head (col ln&3)
        short8 kb[2];
#pragma unroll
        for (int kc = 0; kc < 2; ++kc)
            kb[kc] = *(const short8*)&kqb[(i * 4 + (ln & 3)) * SK + kc * 32 + lg * 8];

        float sv[16];
        float m = -3e38f;
#pragma unroll
        for (int mt = 0; mt < 4; ++mt) {
            const short8 ya0 = *(const short8*)&hy[(mt * 16 + ln) * SY + 0 * 32 + lg * 8];
            const short8 ya1 = *(const short8*)&hy[(mt * 16 + ln) * SY + 1 * 32 + lg * 8];
            f32x4 c = {0.f, 0.f, 0.f, 0.f};
            c = __builtin_amdgcn_mfma_f32_16x16x32_bf16(ya0, kb[0], c, 0, 0, 0);
            c = __builtin_amdgcn_mfma_f32_16x16x32_bf16(ya1, kb[1], c, 0, 0, 0);
#pragma unroll
            for (int r = 0; r < 4; ++r) {
                float s = c[r];                          // 0.25 folded into kqb
                if ((mb64[i] >> (mt * 16 + lg * 4 + r)) & 1ull) s = -1e9f;
                sv[mt * 4 + r] = s;
                m = fmaxf(m, s);
            }
        }
        m = fmaxf(m, __shfl_xor(m, 16));
        m = fmaxf(m, __shfl_xor(m, 32));
        float sum = 0.f;
#pragma unroll
        for (int k = 0; k < 16; ++k) { sv[k] = __expf(sv[k] - m); sum += sv[k]; }
        sum += __shfl_xor(sum, 16);
        sum += __shfl_xor(sum, 32);
        const float inv = 1.f / sum;
        if (ln < 4) {                               // 4 real rows only
#pragma unroll
            for (int mt = 0; mt < 4; ++mt) {
                short4b pk;
#pragma unroll
                for (int r = 0; r < 4; ++r) pk[r] = f2bs(sv[mt * 4 + r] * inv);
                *(short4b*)&pa[ln * SK + mt * 16 + lg * 4] = pk;   // P[h=ln][e]
            }
        }
        LDS_FENCE();
        // pY = P @ Y  (A row m -> head m&3 via replicated read)
        short8 pf[2];
#pragma unroll
        for (int kc = 0; kc < 2; ++kc)
            pf[kc] = *(const short8*)&pa[(ln & 3) * SK + kc * 32 + lg * 8];
#pragma unroll
        for (int ct = 0; ct < 4; ++ct) {
            f32x4 c = {0.f, 0.f, 0.f, 0.f};
#pragma unroll
            for (int kc = 0; kc < 2; ++kc) {
                short8 yv;
#pragma unroll
                for (int j = 0; j < 8; ++j)
                    yv[j] = hy[(kc * 32 + lg * 8 + j) * SY + ct * 16 + ln];
                c = __builtin_amdgcn_mfma_f32_16x16x32_bf16(pf[kc], yv, c, 0, 0, 0);
            }
            if (lg == 0) {
#pragma unroll
                for (int r = 0; r < 4; ++r)
                    py[(r * 2 + i) * SK + ct * 16 + ln] = f2bs(c[r]);   // [h][b][f]
            }
        }
        LDS_FENCE();
    }

    // ================= tail: o64 = pY @ Wv (head-sliced), result ============
#pragma unroll
    for (int ct = 0; ct < 4; ++ct) {              // ct = head h; cols 16h..16h+16
        short8 af[2];
#pragma unroll
        for (int kc = 0; kc < 2; ++kc)
            af[kc] = *(const short8*)&py[(ct * 2 + (ln & 1)) * SK + kc * 32 + lg * 8];
        f32x4 c = {0.f, 0.f, 0.f, 0.f};
#pragma unroll
        for (int kc = 0; kc < 2; ++kc) {
            const short8 bfr = ldws8(ws + WS_WVT + (ct * 16 + ln) * 64 + kc * 32 + lg * 8);
            c = __builtin_amdgcn_mfma_f32_16x16x32_bf16(af[kc], bfr, c, 0, 0, 0);
        }
        if (lg == 0) {
#pragma unroll
            for (int r = 0; r < 2; ++r)
                cbob[r * SK + ct * 16 + ln] = f2bs(c[r]);   // ob rows = batch
        }
    }
    LDS_FENCE();
    short8 oa[2];
#pragma unroll
    for (int kc = 0; kc < 2; ++kc)
        oa[kc] = *(const short8*)&cbob[(ln & 1) * SK + kc * 32 + lg * 8];
#pragma unroll
    for (int ct = 0; ct < 4; ++ct) {              // result = o64 @ Wc + ego, *0.5
        f32x4 c = {0.f, 0.f, 0.f, 0.f};
#pragma unroll
        for (int kc = 0; kc < 2; ++kc) {
            const short8 bfr = ldws8(ws + WS_WCT + (ct * 16 + ln) * 64 + kc * 32 + lg * 8);
            c = __builtin_amdgcn_mfma_f32_16x16x32_bf16(oa[kc], bfr, c, 0, 0, 0);
        }
        if (lg == 0) {
#pragma unroll
            for (int r = 0; r < 2; ++r)
                out[(size_t)(gb + r) * 64 + ct * 16 + ln] = (c[r] + egoR[ct][r]) * 0.5f;
        }
    }
}

extern "C" void kernel_launch(void* const* d_in, const int* in_sizes, int n_in,
                              void* d_out, int out_size, void* d_ws, size_t ws_size,
                              hipStream_t stream) {
    const float* x      = (const float*)d_in[0];
    const float* ego_w0 = (const float*)d_in[1];
    const float* ego_b0 = (const float*)d_in[2];
    const float* ego_w1 = (const float*)d_in[3];
    const float* ego_b1 = (const float*)d_in[4];
    const float* oth_w0 = (const float*)d_in[5];
    const float* oth_b0 = (const float*)d_in[6];
    const float* oth_w1 = (const float*)d_in[7];
    const float* oth_b1 = (const float*)d_in[8];
    const float* Wk     = (const float*)d_in[9];
    const float* Wv     = (const float*)d_in[10];
    const float* Wq     = (const float*)d_in[11];
    const float* Wc     = (const float*)d_in[12];

    unsigned short* ws = (unsigned short*)d_ws;   // needs 67584 B
    pack_ws<<<320, 64, 0, stream>>>(ego_w0, ego_w1, oth_w0, oth_w1,
                                    Wk, Wv, Wq, Wc, ws);
    ego_attn_kernel<<<4096, 64, 0, stream>>>(
        x, ego_b0, ego_b1, oth_b0, oth_b1, ws, (float*)d_out);
}

// Round 6
// 121.540 us; speedup vs baseline: 1.4934x; 1.1123x over previous
//
#include <hip/hip_runtime.h>
#include <hip/hip_bf16.h>

// EgoAttentionNetwork: B=8192, E=64, F_IN=7, D=64, H=4, HD=16. fp32 in/out.
// Round 12: I-CACHE theory. r6's fully-unrolled kernel is ~8K instrs = ~64KB
// of code, 2x the 32KB L1I. Evidence: no pipe >40% busy yet 100K cy/wave;
// r10 (+40% code) -50% perf despite fewer LDS ops; r7/r11 (staggered wave
// phases) regressed at HIGHER occupancy; r8 (code-neutral) exactly neutral.
// Fix: keep r6/r8 EXACT structure/math/fences/grid (2048x64, 8 blocks/CU),
// but roll the 4-batch loop (#pragma unroll 1) so the ~11KB body appears
// once, and unroll KQ only 4-wide. Rolled loop needs no runtime reg-array
// indexing: x A-frags staged in LDS xld (4KB, written at prefetch), masks as
// 4 ballots in LDS (32B), egoR in LDS f32 (1KB). Code ~64KB -> ~22KB.
// LDS total 19552B -> still 8 blocks/CU (occupancy controlled experiment).

typedef __attribute__((ext_vector_type(8))) short short8;   // 8 bf16
typedef __attribute__((ext_vector_type(4))) short short4b;  // 4 bf16
typedef __attribute__((ext_vector_type(4))) float f32x4;

#define SY 72          // u16 row stride for LDS matrix buffers

// wave-local LDS fence: order DS ops at compile time, drain LDS counter only.
#define LDS_FENCE() asm volatile("s_waitcnt lgkmcnt(0)" ::: "memory")

// ws offsets in u16 units (total 33792 u16 = 67584 B)
#define WS_G    0      // [256][64]  G[(h*64+f)][j]
#define WS_EGW0 16384  // [64][8]    ego_w0^T (k<7 real, k=7 zero)
#define WS_EGW1 16896  // [64][64]   ego_w1^T
#define WS_WVT  20992  // [64][64]   Wv^T
#define WS_WCT  25088  // [64][64]   Wc^T
#define WS_W0T  29184  // [64][8]    oth_w0^T
#define WS_W1T  29696  // [64][64]   oth_w1^T

__device__ __forceinline__ short f2bs(float x) {
    __hip_bfloat16 h = __float2bfloat16(x);
    return __builtin_bit_cast(short, h);
}
__device__ __forceinline__ unsigned short f2u(float x) {
    __hip_bfloat16 h = __float2bfloat16(x);
    return __builtin_bit_cast(unsigned short, h);
}
__device__ __forceinline__ short8 ldws8(const unsigned short* p) {
    return *(const short8*)p;   // 16B-aligned -> global_load_dwordx4
}

__global__ void pack_ws(const float* __restrict__ ego_w0, const float* __restrict__ ego_w1,
                        const float* __restrict__ oth_w0, const float* __restrict__ oth_w1,
                        const float* __restrict__ Wk, const float* __restrict__ Wv,
                        const float* __restrict__ Wq, const float* __restrict__ Wc,
                        unsigned short* __restrict__ ws) {
    const int blk = blockIdx.x, t = threadIdx.x;
    if (blk < 256) {
        // G[n=(h*64+f)][j] = sum_d Wq[j][16h+d] * Wk[f][16h+d]
        const int n = blk, h = n >> 6, f = n & 63, j = t;
        float a = 0.f;
#pragma unroll
        for (int d = 0; d < 16; ++d)
            a = fmaf(Wq[j * 64 + h * 16 + d], Wk[f * 64 + h * 16 + d], a);
        ws[WS_G + n * 64 + j] = f2u(a);
    } else {
        const int n = blk - 256, k = t;    // n = output col, k = contraction idx
        ws[WS_EGW1 + n * 64 + k] = f2u(ego_w1[k * 64 + n]);
        ws[WS_WVT  + n * 64 + k] = f2u(Wv[k * 64 + n]);
        ws[WS_WCT  + n * 64 + k] = f2u(Wc[k * 64 + n]);
        ws[WS_W1T  + n * 64 + k] = f2u(oth_w1[k * 64 + n]);
        if (k < 8) {
            ws[WS_EGW0 + n * 8 + k] = (k < 7) ? f2u(ego_w0[k * 64 + n]) : 0;
            ws[WS_W0T  + n * 8 + k] = (k < 7) ? f2u(oth_w0[k * 64 + n]) : 0;
        }
    }
}

__global__ __launch_bounds__(64, 2)
void ego_attn_kernel(const float* __restrict__ x,
                     const float* __restrict__ ego_b0, const float* __restrict__ ego_b1,
                     const float* __restrict__ oth_b0, const float* __restrict__ oth_b1,
                     const unsigned short* __restrict__ ws,
                     float* __restrict__ out)
{
    __shared__ __align__(16) short hy[64 * SY];    // H/Y; also chainbuf + ob alias rows 0-3
    __shared__ __align__(16) short kqb[16 * SY];   // row b*4+h : kq[b][h][f]*0.25
    __shared__ __align__(16) short pa[4 * SY];     // P[h][e], 4 real rows
    __shared__ __align__(16) short py[16 * SY];    // row h*4+b : pY[b][h][f]
    __shared__ __align__(16) short xld[4 * 64 * 8];// x rows bf16 (7 + pad), per batch
    __shared__ __align__(16) float egf[4 * 64];    // egoR f32, row = batch
    __shared__ unsigned long long mball[4];        // ballot mask per batch

    const int lane = threadIdx.x;
    const int lg = lane >> 4, ln = lane & 15;
    const int gb = blockIdx.x * 4;                 // 4 batches per wave
    const short8 z8 = {0, 0, 0, 0, 0, 0, 0, 0};

    // ---- persistent weight frags (16B vector loads from ws) ----
    short8 w0f[4], w1f[2][4];
#pragma unroll
    for (int ct = 0; ct < 4; ++ct)
        w0f[ct] = (lg == 0) ? ldws8(ws + WS_W0T + (ct * 16 + ln) * 8) : z8;
#pragma unroll
    for (int kc = 0; kc < 2; ++kc)
#pragma unroll
        for (int ct = 0; ct < 4; ++ct)
            w1f[kc][ct] = ldws8(ws + WS_W1T + (ct * 16 + ln) * 64 + kc * 32 + lg * 8);
    float b0v[4], b1v[4], eb0v[4], eb1v[4];
#pragma unroll
    for (int ct = 0; ct < 4; ++ct) {
        b0v[ct]  = oth_b0[ct * 16 + ln];
        b1v[ct]  = oth_b1[ct * 16 + ln];
        eb0v[ct] = ego_b0[ct * 16 + ln];
        eb1v[ct] = ego_b1[ct * 16 + ln];
    }

    // ---- prefetch: x rows -> xld (bf16, slot7=0), ballots -> mball ----
#pragma unroll
    for (int i = 0; i < 4; ++i) {
        const float* xr = x + (size_t)(gb + i) * 448 + lane * 7;   // lane = e
        const float v0 = xr[0];
        const unsigned long long mb = __ballot(v0 < 0.5f);
        if (lane == 0) mball[i] = mb;
        short8 v;
        v[0] = f2bs(v0);
#pragma unroll
        for (int k = 1; k < 7; ++k) v[k] = f2bs(xr[k]);
        v[7] = 0;
        *(short8*)&xld[((i << 6) | lane) * 8] = v;
    }
    LDS_FENCE();

    // ================= chain: egoL1 -> egoL2 -> KQ ==========================
    short8 xea;                                    // A[m=b][k<7] = x_b row 0
    {
        const short8 t = *(const short8*)&xld[((ln & 3) << 6) * 8];
        xea = (lg == 0 && ln < 4) ? t : z8;
    }
#pragma unroll
    for (int ct = 0; ct < 4; ++ct) {              // Hego = relu(x0 @ ego_w0 + b0)
        const short8 bfr = (lg == 0) ? ldws8(ws + WS_EGW0 + (ct * 16 + ln) * 8) : z8;
        f32x4 c = {eb0v[ct], eb0v[ct], eb0v[ct], eb0v[ct]};
        c = __builtin_amdgcn_mfma_f32_16x16x32_bf16(xea, bfr, c, 0, 0, 0);
        if (lg == 0) {
#pragma unroll
            for (int r = 0; r < 4; ++r)
                hy[r * SY + ct * 16 + ln] = f2bs(fmaxf(c[r], 0.f));   // chainbuf alias
        }
    }
    LDS_FENCE();
    short8 ha[2];
#pragma unroll
    for (int kc = 0; kc < 2; ++kc)
        ha[kc] = *(const short8*)&hy[(ln & 3) * SY + kc * 32 + lg * 8];
    LDS_FENCE();
#pragma unroll
    for (int ct = 0; ct < 4; ++ct) {              // Ego = relu(Hego @ ego_w1 + b1)
        f32x4 c = {eb1v[ct], eb1v[ct], eb1v[ct], eb1v[ct]};
#pragma unroll
        for (int kc = 0; kc < 2; ++kc) {
            const short8 bfr = ldws8(ws + WS_EGW1 + (ct * 16 + ln) * 64 + kc * 32 + lg * 8);
            c = __builtin_amdgcn_mfma_f32_16x16x32_bf16(ha[kc], bfr, c, 0, 0, 0);
        }
        if (lg == 0) {
#pragma unroll
            for (int r = 0; r < 4; ++r) {
                const float e = fmaxf(c[r], 0.f);
                egf[r * 64 + ct * 16 + ln] = e;                 // f32 for residual
                hy[r * SY + ct * 16 + ln] = f2bs(e);            // bf16 for ea
            }
        }
    }
    LDS_FENCE();
    short8 ea[2];
#pragma unroll
    for (int kc = 0; kc < 2; ++kc)
        ea[kc] = *(const short8*)&hy[(ln & 3) * SY + kc * 32 + lg * 8];

    // KQ[b][n=(h*64+f)] = sum_j Ego[b][j] G[n][j]; fold 0.25 score scale here
#pragma unroll 4
    for (int ctg = 0; ctg < 16; ++ctg) {
        f32x4 c = {0.f, 0.f, 0.f, 0.f};
#pragma unroll
        for (int kc = 0; kc < 2; ++kc) {
            const short8 bfr = ldws8(ws + WS_G + (ctg * 16 + ln) * 64 + kc * 32 + lg * 8);
            c = __builtin_amdgcn_mfma_f32_16x16x32_bf16(ea[kc], bfr, c, 0, 0, 0);
        }
        if (lg == 0) {
            const int h = ctg >> 2, fc = (ctg & 3) * 16 + ln;
#pragma unroll
            for (int r = 0; r < 4; ++r)
                kqb[(r * 4 + h) * SY + fc] = f2bs(c[r] * 0.25f);
        }
    }
    LDS_FENCE();

    // ============ per-batch body (ROLLED: appears once in code) =============
#pragma unroll 1
    for (int i = 0; i < 4; ++i) {
        // A-frags for this batch from xld (broadcast reads, zero for lg>0)
        short8 xa[4];
#pragma unroll
        for (int mt = 0; mt < 4; ++mt) {
            const short8 t = *(const short8*)&xld[((i << 6) | (mt * 16 + ln)) * 8];
            xa[mt] = (lg == 0) ? t : z8;
        }
        const unsigned long long mb = mball[i];

        // P1: H = relu(X @ W0 + b0)
#pragma unroll
        for (int mt = 0; mt < 4; ++mt)
#pragma unroll
            for (int ct = 0; ct < 4; ++ct) {
                f32x4 c = {b0v[ct], b0v[ct], b0v[ct], b0v[ct]};
                c = __builtin_amdgcn_mfma_f32_16x16x32_bf16(xa[mt], w0f[ct], c, 0, 0, 0);
#pragma unroll
                for (int r = 0; r < 4; ++r)
                    hy[(mt * 16 + lg * 4 + r) * SY + ct * 16 + ln] = f2bs(fmaxf(c[r], 0.f));
            }
        LDS_FENCE();
        short8 a2[4][2];
#pragma unroll
        for (int mt = 0; mt < 4; ++mt)
#pragma unroll
            for (int kc = 0; kc < 2; ++kc)
                a2[mt][kc] = *(const short8*)&hy[(mt * 16 + ln) * SY + kc * 32 + lg * 8];
        LDS_FENCE();
        // P2: Y = relu(H @ W1 + b1); then row 0 <- ego_i (from egf)
#pragma unroll
        for (int ct = 0; ct < 4; ++ct)
#pragma unroll
            for (int mt = 0; mt < 4; ++mt) {
                f32x4 c = {b1v[ct], b1v[ct], b1v[ct], b1v[ct]};
                c = __builtin_amdgcn_mfma_f32_16x16x32_bf16(a2[mt][0], w1f[0][ct], c, 0, 0, 0);
                c = __builtin_amdgcn_mfma_f32_16x16x32_bf16(a2[mt][1], w1f[1][ct], c, 0, 0, 0);
#pragma unroll
                for (int r = 0; r < 4; ++r)
                    hy[(mt * 16 + lg * 4 + r) * SY + ct * 16 + ln] = f2bs(fmaxf(c[r], 0.f));
            }
        if (lg == 0) {
#pragma unroll
            for (int ct = 0; ct < 4; ++ct)
                hy[ct * 16 + ln] = f2bs(egf[i * 64 + ct * 16 + ln]);  // Y row 0 = ego_i
        }
        LDS_FENCE();
        // S = Y @ kq_i^T (n=h, cols>=4 copies); softmax per head (h = ln&3)
        short8 kb[2];
#pragma unroll
        for (int kc = 0; kc < 2; ++kc)
            kb[kc] = *(const short8*)&kqb[(i * 4 + (ln & 3)) * SY + kc * 32 + lg * 8];

        float sv[16];
        float m = -3e38f;
#pragma unroll
        for (int mt = 0; mt < 4; ++mt) {
            const short8 ya0 = *(const short8*)&hy[(mt * 16 + ln) * SY + 0 * 32 + lg * 8];
            const short8 ya1 = *(const short8*)&hy[(mt * 16 + ln) * SY + 1 * 32 + lg * 8];
            f32x4 c = {0.f, 0.f, 0.f, 0.f};
            c = __builtin_amdgcn_mfma_f32_16x16x32_bf16(ya0, kb[0], c, 0, 0, 0);
            c = __builtin_amdgcn_mfma_f32_16x16x32_bf16(ya1, kb[1], c, 0, 0, 0);
#pragma unroll
            for (int r = 0; r < 4; ++r) {
                float s = c[r];                    // 0.25 folded into kqb
                if ((mb >> (mt * 16 + lg * 4 + r)) & 1ull) s = -1e9f;
                sv[mt * 4 + r] = s;
                m = fmaxf(m, s);
            }
        }
        m = fmaxf(m, __shfl_xor(m, 16));
        m = fmaxf(m, __shfl_xor(m, 32));
        float sum = 0.f;
#pragma unroll
        for (int k = 0; k < 16; ++k) { sv[k] = __expf(sv[k] - m); sum += sv[k]; }
        sum += __shfl_xor(sum, 16);
        sum += __shfl_xor(sum, 32);
        const float inv = 1.f / sum;
        if (ln < 4) {                              // 4 real P rows (h = ln)
#pragma unroll
            for (int mt = 0; mt < 4; ++mt) {
                short4b pk;
#pragma unroll
                for (int r = 0; r < 4; ++r) pk[r] = f2bs(sv[mt * 4 + r] * inv);
                *(short4b*)&pa[ln * SY + mt * 16 + lg * 4] = pk;
            }
        }
        LDS_FENCE();
        // pY = P @ Y (A rows replicated via ln&3)
        short8 pf[2];
#pragma unroll
        for (int kc = 0; kc < 2; ++kc)
            pf[kc] = *(const short8*)&pa[(ln & 3) * SY + kc * 32 + lg * 8];
#pragma unroll
        for (int ct = 0; ct < 4; ++ct) {
            f32x4 c = {0.f, 0.f, 0.f, 0.f};
#pragma unroll
            for (int kc = 0; kc < 2; ++kc) {
                short8 yv;
#pragma unroll
                for (int j = 0; j < 8; ++j)
                    yv[j] = hy[(kc * 32 + lg * 8 + j) * SY + ct * 16 + ln];
                c = __builtin_amdgcn_mfma_f32_16x16x32_bf16(pf[kc], yv, c, 0, 0, 0);
            }
            if (lg == 0) {
#pragma unroll
                for (int r = 0; r < 4; ++r)
                    py[(r * 4 + i) * SY + ct * 16 + ln] = f2bs(c[r]);   // row h*4+b
            }
        }
        LDS_FENCE();
    }

    // ================= tail: o64 = pY @ Wv (head-sliced), result ============
#pragma unroll
    for (int ct = 0; ct < 4; ++ct) {              // ct = head h; cols 16h..16h+16
        short8 af[2];
#pragma unroll
        for (int kc = 0; kc < 2; ++kc)
            af[kc] = *(const short8*)&py[(ct * 4 + (ln & 3)) * SY + kc * 32 + lg * 8];
        f32x4 c = {0.f, 0.f, 0.f, 0.f};
#pragma unroll
        for (int kc = 0; kc < 2; ++kc) {
            const short8 bfr = ldws8(ws + WS_WVT + (ct * 16 + ln) * 64 + kc * 32 + lg * 8);
            c = __builtin_amdgcn_mfma_f32_16x16x32_bf16(af[kc], bfr, c, 0, 0, 0);
        }
        if (lg == 0) {
#pragma unroll
            for (int r = 0; r < 4; ++r)
                hy[r * SY + ct * 16 + ln] = f2bs(c[r]);         // ob alias rows b
        }
    }
    LDS_FENCE();
    short8 oa[2];
#pragma unroll
    for (int kc = 0; kc < 2; ++kc)
        oa[kc] = *(const short8*)&hy[(ln & 3) * SY + kc * 32 + lg * 8];
#pragma unroll
    for (int ct = 0; ct < 4; ++ct) {              // result = o64 @ Wc + ego, *0.5
        f32x4 c = {0.f, 0.f, 0.f, 0.f};
#pragma unroll
        for (int kc = 0; kc < 2; ++kc) {
            const short8 bfr = ldws8(ws + WS_WCT + (ct * 16 + ln) * 64 + kc * 32 + lg * 8);
            c = __builtin_amdgcn_mfma_f32_16x16x32_bf16(oa[kc], bfr, c, 0, 0, 0);
        }
        if (lg == 0) {
#pragma unroll
            for (int r = 0; r < 4; ++r)
                out[(size_t)(gb + r) * 64 + ct * 16 + ln] = (c[r] + egf[r * 64 + ct * 16 + ln]) * 0.5f;
        }
    }
}

extern "C" void kernel_launch(void* const* d_in, const int* in_sizes, int n_in,
                              void* d_out, int out_size, void* d_ws, size_t ws_size,
                              hipStream_t stream) {
    const float* x      = (const float*)d_in[0];
    const float* ego_w0 = (const float*)d_in[1];
    const float* ego_b0 = (const float*)d_in[2];
    const float* ego_w1 = (const float*)d_in[3];
    const float* ego_b1 = (const float*)d_in[4];
    const float* oth_w0 = (const float*)d_in[5];
    const float* oth_b0 = (const float*)d_in[6];
    const float* oth_w1 = (const float*)d_in[7];
    const float* oth_b1 = (const float*)d_in[8];
    const float* Wk     = (const float*)d_in[9];
    const float* Wv     = (const float*)d_in[10];
    const float* Wq     = (const float*)d_in[11];
    const float* Wc     = (const float*)d_in[12];

    unsigned short* ws = (unsigned short*)d_ws;   // needs 67584 B
    pack_ws<<<320, 64, 0, stream>>>(ego_w0, ego_w1, oth_w0, oth_w1,
                                    Wk, Wv, Wq, Wc, ws);
    ego_attn_kernel<<<2048, 64, 0, stream>>>(
        x, ego_b0, ego_b1, oth_b0, oth_b1, ws, (float*)d_out);
}